// Round 11
// baseline (170.068 us; speedup 1.0000x reference)
//
#include <hip/hip_runtime.h>
#include <hip/hip_bf16.h>

typedef unsigned char u8;
typedef unsigned short u16;
typedef unsigned int u32;
typedef long long s64;
typedef float f32x4 __attribute__((ext_vector_type(4)));
typedef long long s64x2 __attribute__((ext_vector_type(2)));

#define MEM    2000
#define FEA    256
#define SLSTR  2064      // fp8 a row stride (bytes), 16B-aligned
#define OSTR   265       // out-stage row stride (f32)
#define XRS    264       // xr fp8 row stride (bytes)
#define POOLSZ 66048     // a-matrix 32*SLSTR; xr + out-stage overlap inside
#define OUTN   8388608   // 32*256*32*32

// exact f32 -> e4m3fn (RNE) incl subnormals
__device__ __forceinline__ u32 f2e4m3(float x) {
    float ax = fabsf(x);
    u32 s = (__builtin_bit_cast(u32, x) >> 24) & 0x80u;
    if (ax >= 448.f) return s | 0x7e;
    if (ax < 0.015625f) {
        int q = (int)rintf(ax * 512.f);
        return s | (u32)q;
    }
    int e = (int)(__builtin_bit_cast(u32, ax) >> 23) - 127;
    float scale = __builtin_bit_cast(float, (u32)((127 - e + 3) << 23));
    int q = (int)rintf(ax * scale);
    int E = e + 7;
    if (q == 16) { q = 8; E += 1; if (E > 15) return s | 0x7e; }
    return s | (u32)(E << 3) | (u32)(q & 7);
}
// fast f32 -> e4m3fn for v in {0} U [0.15, 64]
__device__ __forceinline__ u32 f2e4m3_fast(float v) {
    u32 u = __builtin_bit_cast(u32, v);
    u += 0x0007FFFFu + ((u >> 20) & 1u);
    int bb = (int)(u >> 20) - 0x3C0;
    return bb < 0 ? 0u : (u32)bb;
}

// ---------------- prep (identical to round 10) ----------------
__global__ __launch_bounds__(256) void prep_kernel(const float* __restrict__ W,
                                                   u8* __restrict__ WTc,
                                                   u8* __restrict__ Wc,
                                                   float* __restrict__ sqv,
                                                   float* __restrict__ loss) {
    const int blk = blockIdx.x, t = threadIdx.x;
    const int m0 = blk * 8;
    {
        const int sl = t >> 5, cl = t & 31;
        const int slot = m0 + sl;
        const int ch0 = cl * 8;
        const float* wr = W + slot * 256 + ch0;
        f32x4 v0 = *(const f32x4*)wr;
        f32x4 v1 = *(const f32x4*)(wr + 4);
        float ss = v0[0]*v0[0] + v0[1]*v0[1] + v0[2]*v0[2] + v0[3]*v0[3]
                 + v1[0]*v1[0] + v1[1]*v1[1] + v1[2]*v1[2] + v1[3]*v1[3];
        ss += __shfl_xor(ss, 1); ss += __shfl_xor(ss, 2); ss += __shfl_xor(ss, 4);
        ss += __shfl_xor(ss, 8); ss += __shfl_xor(ss, 16);
        if (cl == 0) sqv[slot] = ss;
        const int c = slot >> 6, s = slot & 63;
        const int kk = cl >> 2, agp = cl & 3;
        const int kp = kk >> 1, klo = kk & 1;
        u32 lo = 0, hi = 0;
#pragma unroll
        for (int i = 0; i < 4; ++i) {
            lo |= f2e4m3(v0[i] * 16.f) << (i * 8);
            hi |= f2e4m3(v1[i] * 16.f) << (i * 8);
        }
        u8* dst = Wc + c * 16384 + (size_t)((kp * 4 + agp) * 64 + s) * 16 + klo * 8;
        *(u32*)dst = lo;
        *(u32*)(dst + 4) = hi;
    }
    {
        const int ch = t;
        const int chunk = m0 >> 6;
        const int kl0 = m0 & 63;
        const int klo = kl0 >> 5, agp = (kl0 & 31) >> 3;
        u32 lo = 0, hi = 0;
#pragma unroll
        for (int i = 0; i < 8; ++i) {
            u32 bb = f2e4m3(W[(m0 + i) * 256 + ch] * 16.f);
            if (i < 4) lo |= bb << (i * 8); else hi |= bb << ((i - 4) * 8);
        }
        u8* dst = WTc + chunk * 16384 + ch * 64 + agp * 16 + klo * 8;
        *(u32*)dst = lo;
        *(u32*)(dst + 4) = hi;
    }
    if (blk == 0 && t == 0) {
        loss[0] = 0.0f;
        loss[1] = -2000.0f / (2000.0f * 1999.0f);
    }
}

// ---------------- main fused kernel: 32 rows/block, 1024 blocks, explicit SW pipeline ----------------
__global__ __launch_bounds__(512, 1) void main_kernel(
        const float* __restrict__ inp, const float* __restrict__ posb,
        const u8* __restrict__ Wc, const u8* __restrict__ WTc,
        const float* __restrict__ sqv, float* __restrict__ out,
        float* __restrict__ loss) {
    __shared__ __align__(16) u8 pool[POOLSZ];
    __shared__ float sPM[4][32];
    __shared__ int   sPI[4][32];
    __shared__ float sPZ[4][32];
    __shared__ float sPD[4][32];
    __shared__ float sSS[8][32];
    __shared__ float sMax[32];
    __shared__ float sThr[32];
    __shared__ float sInv[32];

    const int t = threadIdx.x;
    const int w = t >> 6, lane = t & 63;
    const int ar = lane & 15, ag = lane >> 4;
    const int blk = blockIdx.x, b = blk >> 5, hw0 = (blk & 31) << 5;
    const int prot = ((blk >> 3) & 15) * 2;      // chunk rotation for L2 spread
    const int q = w & 3, rt = w >> 2;
    const int row_a = rt * 16 + ar;

    // ---- phase A: stage xr as fp8 (x*4) at pool[0, 8448); per-row sum(x^2) ----
    {
        const int hw = t & 31, cg = t >> 5;
        const float* ip = inp + (size_t)b * 262144 + hw0 + hw;
        const float* pp = posb + hw0 + hw;
        float ss = 0.f;
        u8* xrow = pool + hw * XRS + cg * 16;
#pragma unroll
        for (int j = 0; j < 8; ++j) {
            const int ch = cg * 16 + 2 * j;
            float v0 = ip[ch * 1024] + pp[ch * 1024];
            float v1 = ip[(ch + 1) * 1024] + pp[(ch + 1) * 1024];
            ss += v0 * v0 + v1 * v1;
            u16 pk2 = (u16)(f2e4m3(v0 * 4.f) | (f2e4m3(v1 * 4.f) << 8));
            *(u16*)(xrow + 2 * j) = pk2;
        }
        ss += __shfl_xor(ss, 32);
        if (lane < 32) sSS[w][lane] = ss;
    }
    __syncthreads();

    // ---- xr B-fragments: row_a, full K=256 (8 x 8B) ----
    s64 xB[8];
#pragma unroll
    for (int kk = 0; kk < 8; ++kk)
        xB[kk] = *(const s64*)(pool + row_a * XRS + kk * 32 + ag * 8);

    // ---- GEMM1 (fp8, global->reg, explicit 2-chunk double-buffer) ----
    f32x4 acc[32];
    const int c31 = (31 - prot) & 31;
    {
        const u8* wbase = Wc + ag * 1024 + (q * 16 + ar) * 16;
        s64x2 pA[4], pB[4];
        {
            const u8* p0 = wbase + ((prot) & 31) * 16384;
            pA[0] = *(const s64x2*)(p0);
            pA[1] = *(const s64x2*)(p0 + 4096);
            pA[2] = *(const s64x2*)(p0 + 8192);
            pA[3] = *(const s64x2*)(p0 + 12288);
            const u8* p1 = wbase + ((1 + prot) & 31) * 16384;
            pB[0] = *(const s64x2*)(p1);
            pB[1] = *(const s64x2*)(p1 + 4096);
            pB[2] = *(const s64x2*)(p1 + 8192);
            pB[3] = *(const s64x2*)(p1 + 12288);
        }
#pragma unroll
        for (int c = 0; c < 32; c += 2) {
            // compute chunk c from pA
            s64x2 w0 = pA[0], w1 = pA[1], w2 = pA[2], w3 = pA[3];
            if (c + 2 < 32) {
                const u8* p = wbase + ((c + 2 + prot) & 31) * 16384;
                pA[0] = *(const s64x2*)(p);
                pA[1] = *(const s64x2*)(p + 4096);
                pA[2] = *(const s64x2*)(p + 8192);
                pA[3] = *(const s64x2*)(p + 12288);
            }
            f32x4 a = {0.f, 0.f, 0.f, 0.f};
            a = __builtin_amdgcn_mfma_f32_16x16x32_fp8_fp8(w0[0], xB[0], a, 0, 0, 0);
            a = __builtin_amdgcn_mfma_f32_16x16x32_fp8_fp8(w0[1], xB[1], a, 0, 0, 0);
            a = __builtin_amdgcn_mfma_f32_16x16x32_fp8_fp8(w1[0], xB[2], a, 0, 0, 0);
            a = __builtin_amdgcn_mfma_f32_16x16x32_fp8_fp8(w1[1], xB[3], a, 0, 0, 0);
            a = __builtin_amdgcn_mfma_f32_16x16x32_fp8_fp8(w2[0], xB[4], a, 0, 0, 0);
            a = __builtin_amdgcn_mfma_f32_16x16x32_fp8_fp8(w2[1], xB[5], a, 0, 0, 0);
            a = __builtin_amdgcn_mfma_f32_16x16x32_fp8_fp8(w3[0], xB[6], a, 0, 0, 0);
            a = __builtin_amdgcn_mfma_f32_16x16x32_fp8_fp8(w3[1], xB[7], a, 0, 0, 0);
            if (c == c31 && q != 0) { a[0] = -3e38f; a[1] = -3e38f; a[2] = -3e38f; a[3] = -3e38f; }
            acc[c] = a;
            // compute chunk c+1 from pB
            s64x2 v0 = pB[0], v1 = pB[1], v2 = pB[2], v3 = pB[3];
            if (c + 3 < 32) {
                const u8* p = wbase + ((c + 3 + prot) & 31) * 16384;
                pB[0] = *(const s64x2*)(p);
                pB[1] = *(const s64x2*)(p + 4096);
                pB[2] = *(const s64x2*)(p + 8192);
                pB[3] = *(const s64x2*)(p + 12288);
            }
            f32x4 bacc = {0.f, 0.f, 0.f, 0.f};
            bacc = __builtin_amdgcn_mfma_f32_16x16x32_fp8_fp8(v0[0], xB[0], bacc, 0, 0, 0);
            bacc = __builtin_amdgcn_mfma_f32_16x16x32_fp8_fp8(v0[1], xB[1], bacc, 0, 0, 0);
            bacc = __builtin_amdgcn_mfma_f32_16x16x32_fp8_fp8(v1[0], xB[2], bacc, 0, 0, 0);
            bacc = __builtin_amdgcn_mfma_f32_16x16x32_fp8_fp8(v1[1], xB[3], bacc, 0, 0, 0);
            bacc = __builtin_amdgcn_mfma_f32_16x16x32_fp8_fp8(v2[0], xB[4], bacc, 0, 0, 0);
            bacc = __builtin_amdgcn_mfma_f32_16x16x32_fp8_fp8(v2[1], xB[5], bacc, 0, 0, 0);
            bacc = __builtin_amdgcn_mfma_f32_16x16x32_fp8_fp8(v3[0], xB[6], bacc, 0, 0, 0);
            bacc = __builtin_amdgcn_mfma_f32_16x16x32_fp8_fp8(v3[1], xB[7], bacc, 0, 0, 0);
            if (c + 1 == c31 && q != 0) { bacc[0] = -3e38f; bacc[1] = -3e38f; bacc[2] = -3e38f; bacc[3] = -3e38f; }
            acc[c + 1] = bacc;
        }
    }

    // ---- per-thread max + argmax (one row per thread) ----
    {
        float bm = -3e38f; int bi = 0x7fffffff;
#pragma unroll
        for (int c = 0; c < 32; ++c) {
            const int cb = (((c + prot) & 31) << 6) + q * 16 + ag * 4;
#pragma unroll
            for (int e = 0; e < 4; ++e) {
                float f = acc[c][e];
                int id = cb + e;
                if (f > bm || (f == bm && id < bi)) { bm = f; bi = id; }
            }
        }
#pragma unroll
        for (int d = 16; d < 64; d <<= 1) {
            float om = __shfl_xor(bm, d);
            int   oi = __shfl_xor(bi, d);
            if (om > bm || (om == bm && oi < bi)) { bm = om; bi = oi; }
        }
        if (lane < 16) { sPM[q][rt * 16 + lane] = bm; sPI[q][rt * 16 + lane] = bi; }
    }
    __syncthreads();

    // ---- combine max/argmax + compact loss (logit = acc/64) ----
    if (t < 32) {
        float mx = sPM[0][t]; int bid = sPI[0][t];
#pragma unroll
        for (int qq = 1; qq < 4; ++qq) {
            float m2 = sPM[qq][t]; int i2 = sPI[qq][t];
            if (m2 > mx || (m2 == mx && i2 < bid)) { mx = m2; bid = i2; }
        }
        sMax[t] = mx;
        float ssq = 0.f;
#pragma unroll
        for (int ww = 0; ww < 8; ++ww) ssq += sSS[ww][t];
        float term = ssq - 2.f * (mx * 0.015625f) + sqv[bid];
#pragma unroll
        for (int d = 1; d < 32; d <<= 1) term += __shfl_xor(term, d);
        if (t == 0) atomicAdd(loss, term * (1.0f / 8388608.0f));
    }
    __syncthreads();

    // ---- exp (in-place, scale 1/64) + Z ----
    {
        const float mxv = sMax[row_a];
        float z = 0.f;
#pragma unroll
        for (int c = 0; c < 32; ++c)
#pragma unroll
            for (int e = 0; e < 4; ++e) {
                float a_ = __expf((acc[c][e] - mxv) * 0.015625f);
                acc[c][e] = a_;
                z += a_;
            }
        z += __shfl_xor(z, 16); z += __shfl_xor(z, 32);
        if (lane < 16) sPZ[q][rt * 16 + lane] = z;
    }
    __syncthreads();
    if (t < 32) sThr[t] = 0.0025f * (sPZ[0][t] + sPZ[1][t] + sPZ[2][t] + sPZ[3][t]);
    __syncthreads();

    // ---- shrink mask + denom + packed fp8 a-write (u32/chunk, paired-k layout) ----
    {
        const float thrv = sThr[row_a];
        const int newoff = (((q * 2 + (ag >> 1)) & 3) << 4) | ((q >> 1) << 3) | ((ag & 1) << 2);
        const int rowbase = row_a * SLSTR + newoff;
        float den = 0.f;
#pragma unroll
        for (int c = 0; c < 32; ++c) {
            const int off = rowbase + (((c + prot) & 31) << 6);
            u32 pk = 0;
#pragma unroll
            for (int e = 0; e < 4; ++e) {
                float a_ = acc[c][e];
                if (a_ > thrv) { den += a_; pk |= f2e4m3_fast(a_ * 64.f) << (e * 8); }
            }
            *(u32*)(pool + off) = pk;
        }
        den += __shfl_xor(den, 16); den += __shfl_xor(den, 32);
        if (lane < 16) sPD[q][rt * 16 + lane] = den;
    }
    __syncthreads();
    if (t < 32) {
        float dd = sPD[0][t] + sPD[1][t] + sPD[2][t] + sPD[3][t];
        sInv[t] = dd > 0.f ? 1.0f / (1024.0f * dd) : 0.0f;
    }
    __syncthreads();

    // ---- GEMM2: A from LDS (depth-2 prefetch), B from global (depth-4 prefetch) ----
    const int ch0 = (w * 2) * 16 + ar;
    const int ch1 = ch0 + 16;
    const u8* sLr0 = pool + ar * SLSTR + ag * 16;
    const u8* sLr1 = pool + (16 + ar) * SLSTR + ag * 16;
    const u8* wt0 = WTc + ch0 * 64 + ag * 16;
    const u8* wt1 = WTc + ch1 * 64 + ag * 16;
    f32x4 o00 = {0.f,0.f,0.f,0.f}, o01 = {0.f,0.f,0.f,0.f};
    f32x4 o10 = {0.f,0.f,0.f,0.f}, o11 = {0.f,0.f,0.f,0.f};
    {
        s64x2 Bb0[4], Bb1[4], Ab0[2], Ab1[2];
#pragma unroll
        for (int u = 0; u < 4; ++u) {
            const int pc = (u + prot) & 31;
            Bb0[u] = *(const s64x2*)(wt0 + pc * 16384);
            Bb1[u] = *(const s64x2*)(wt1 + pc * 16384);
        }
#pragma unroll
        for (int u = 0; u < 2; ++u) {
            const int cc64 = ((u + prot) & 31) << 6;
            Ab0[u] = *(const s64x2*)(sLr0 + cc64);
            Ab1[u] = *(const s64x2*)(sLr1 + cc64);
        }
#pragma unroll
        for (int c = 0; c < 32; ++c) {
            s64x2 B0 = Bb0[c & 3], B1 = Bb1[c & 3];
            s64x2 A0 = Ab0[c & 1], A1 = Ab1[c & 1];
            if (c + 4 < 32) {
                const int pc = (c + 4 + prot) & 31;
                Bb0[c & 3] = *(const s64x2*)(wt0 + pc * 16384);
                Bb1[c & 3] = *(const s64x2*)(wt1 + pc * 16384);
            }
            if (c + 2 < 32) {
                const int cc64 = ((c + 2 + prot) & 31) << 6;
                Ab0[c & 1] = *(const s64x2*)(sLr0 + cc64);
                Ab1[c & 1] = *(const s64x2*)(sLr1 + cc64);
            }
            o00 = __builtin_amdgcn_mfma_f32_16x16x32_fp8_fp8(A0[0], B0[0], o00, 0, 0, 0);
            o00 = __builtin_amdgcn_mfma_f32_16x16x32_fp8_fp8(A0[1], B0[1], o00, 0, 0, 0);
            o01 = __builtin_amdgcn_mfma_f32_16x16x32_fp8_fp8(A1[0], B0[0], o01, 0, 0, 0);
            o01 = __builtin_amdgcn_mfma_f32_16x16x32_fp8_fp8(A1[1], B0[1], o01, 0, 0, 0);
            o10 = __builtin_amdgcn_mfma_f32_16x16x32_fp8_fp8(A0[0], B1[0], o10, 0, 0, 0);
            o10 = __builtin_amdgcn_mfma_f32_16x16x32_fp8_fp8(A0[1], B1[1], o10, 0, 0, 0);
            o11 = __builtin_amdgcn_mfma_f32_16x16x32_fp8_fp8(A1[0], B1[0], o11, 0, 0, 0);
            o11 = __builtin_amdgcn_mfma_f32_16x16x32_fp8_fp8(A1[1], B1[1], o11, 0, 0, 0);
        }
    }
    __syncthreads();   // all a-reads done; reuse pool as f32 out-stage

    {
        float* sO = (float*)pool;
#pragma unroll
        for (int i = 0; i < 4; ++i) {
            int r0 = ag * 4 + i, r1 = 16 + ag * 4 + i;
            sO[r0 * OSTR + ch0] = o00[i] * sInv[r0];
            sO[r1 * OSTR + ch0] = o01[i] * sInv[r1];
            sO[r0 * OSTR + ch1] = o10[i] * sInv[r0];
            sO[r1 * OSTR + ch1] = o11[i] * sInv[r1];
        }
    }
    __syncthreads();
    {
        const float* sO = (const float*)pool;
        const int hw = t & 31, cq = t >> 5;
        float* op = out + (size_t)b * 262144 + hw0 + hw;
#pragma unroll
        for (int i = 0; i < 16; ++i) {
            int ch = cq + (i << 4);
            op[ch * 1024] = sO[hw * OSTR + ch];
        }
    }
}

// ---------------- distance loss from fp8 Wc (paired-k layout) ----------------
__global__ __launch_bounds__(256) void dist_kernel(const u8* __restrict__ Wc,
                                                   const float* __restrict__ sqv,
                                                   float* __restrict__ dl) {
    __shared__ float red[4];
    int t = threadIdx.x, w = t >> 6, lane = t & 63;
    int ar = lane & 15, ag = lane >> 4;
    const int i0 = blockIdx.x << 4;
    const int ci = i0 >> 6, si0 = i0 & 63;
    s64x2 af2[4];
#pragma unroll
    for (int kp = 0; kp < 4; ++kp)
        af2[kp] = *(const s64x2*)(Wc + ci * 16384 + (size_t)((kp * 4 + ag) * 64 + si0 + ar) * 16);
    float sqi[4];
#pragma unroll
    for (int e = 0; e < 4; ++e) sqi[e] = sqv[i0 + ag * 4 + e];
    float sum = 0.f;
    for (int jt = w; jt < 125; jt += 4) {
        const int j0 = jt << 4;
        const int cj = j0 >> 6, sj0 = j0 & 63;
        f32x4 acc = {0.f, 0.f, 0.f, 0.f};
#pragma unroll
        for (int kp = 0; kp < 4; ++kp) {
            s64x2 bf = *(const s64x2*)(Wc + cj * 16384 + (size_t)((kp * 4 + ag) * 64 + sj0 + ar) * 16);
            acc = __builtin_amdgcn_mfma_f32_16x16x32_fp8_fp8(af2[kp][0], bf[0], acc, 0, 0, 0);
            acc = __builtin_amdgcn_mfma_f32_16x16x32_fp8_fp8(af2[kp][1], bf[1], acc, 0, 0, 0);
        }
        float sqj = sqv[j0 + ar];
#pragma unroll
        for (int e = 0; e < 4; ++e) {
            float dist = 1.0f - (sqi[e] + sqj - acc[e] * 0.0078125f);
            sum += dist > 0.f ? dist : 0.f;
        }
    }
#pragma unroll
    for (int d = 1; d < 64; d <<= 1) sum += __shfl_xor(sum, d);
    if (lane == 0) red[w] = sum;
    __syncthreads();
    if (t == 0) {
        float s = red[0] + red[1] + red[2] + red[3];
        atomicAdd(dl, s * (1.0f / (2000.0f * 1999.0f)));
    }
}

extern "C" void kernel_launch(void* const* d_in, const int* in_sizes, int n_in,
                              void* d_out, int out_size, void* d_ws, size_t ws_size,
                              hipStream_t stream) {
    (void)in_sizes; (void)n_in; (void)out_size; (void)ws_size;
    const float* inp  = (const float*)d_in[0];
    const float* W    = (const float*)d_in[2];
    const float* posb = (const float*)d_in[3];
    float* out = (float*)d_out;

    u8* WTc = (u8*)d_ws;                                     // 32*16384 = 524,288 B
    u8* Wc  = (u8*)d_ws + 524288;                            // 32*16384 = 524,288 B
    float* sqv = (float*)((u8*)d_ws + 1048576);              // 2000*4   =   8,000 B

    hipLaunchKernelGGL(prep_kernel, dim3(250), dim3(256), 0, stream, W, WTc, Wc, sqv, out + OUTN);
    hipLaunchKernelGGL(main_kernel, dim3(1024), dim3(512), 0, stream, inp, posb, Wc, WTc, sqv, out, out + OUTN);
    hipLaunchKernelGGL(dist_kernel, dim3(125), dim3(256), 0, stream, Wc, sqv, out + OUTN + 1);
}